// Round 14
// baseline (230.692 us; speedup 1.0000x reference)
//
#include <hip/hip_runtime.h>

#define NN 100000
#define NE 1600000
#define BN_EPS 1e-5f
#define NCOARSE 98   // ceil(NN/1024)
#define SC_CH 2048
#define SPLIT 50000  // src-range phase boundary: each half of q-table = 3.2 MB (fits 4 MB L2)

typedef unsigned int u32;
typedef unsigned short u16;
typedef unsigned char u8;

// ---- workspace layout (bytes) ----
static constexpr size_t OFF_ROW  = 0;                    // (NN+1) ints
static constexpr size_t OFF_CTRL = 512u * 1024;          // ch[0..127], reserve[128..255]
static constexpr size_t OFF_CSR  = 1u << 20;             // NE ints (6.4 MB)
static constexpr size_t OFF_U    = 8u << 20;             // ub bf16 [NN][64] (12.8 MB)
static constexpr size_t OFF_P1   = OFF_U;                // alias: pairs1 dead before ub live
static constexpr size_t OFF_Q0   = 22u << 20;            // u8 (biased int8) [NN][64]
static constexpr size_t OFF_S0   = 30u << 20;            // float [NN]
static constexpr size_t OFF_Q1   = 32u << 20;            // u8 [NN][64]
static constexpr size_t OFF_S1   = 40u << 20;            // float [NN]
static constexpr size_t OFF_MID  = 44u << 20;            // int [NN]: per-node src-phase split point

__device__ __forceinline__ u16 f2bf(float f) {
  u32 u = __float_as_uint(f);
  return (u16)((u + 0x7fffu + ((u >> 16) & 1u)) >> 16);
}
__device__ __forceinline__ float bflo(u32 u) { return __uint_as_float(u << 16); }
__device__ __forceinline__ float bfhi(u32 u) { return __uint_as_float(u & 0xffff0000u); }
__device__ __forceinline__ u32 pkbf(float lo, float hi) {
  return (u32)f2bf(lo) | ((u32)f2bf(hi) << 16);
}
__device__ __forceinline__ float ub0(u32 w) { return (float)(w & 0xffu); }
__device__ __forceinline__ float ub1(u32 w) { return (float)((w >> 8) & 0xffu); }
__device__ __forceinline__ float ub2(u32 w) { return (float)((w >> 16) & 0xffu); }
__device__ __forceinline__ float ub3(u32 w) { return (float)((w >> 24) & 0xffu); }

// ---- MFMA types ----
typedef __bf16 bf16x8 __attribute__((ext_vector_type(8)));
typedef float f32x4 __attribute__((ext_vector_type(4)));
union FragCvt { uint4 u; bf16x8 b; u16 s[8]; };
__device__ __forceinline__ bf16x8 frag_u16(const u16* p) {
  FragCvt c; c.u = *(const uint4*)p; return c.b;
}

// quantize 8 bf16 (as uint4) to biased-u8 x8 given inv = 127/rowmax
__device__ __forceinline__ uint2 q8b(uint4 hv, float inv) {
  int q0 = (int)rintf(bflo(hv.x) * inv) + 128, q1 = (int)rintf(bfhi(hv.x) * inv) + 128;
  int q2 = (int)rintf(bflo(hv.y) * inv) + 128, q3 = (int)rintf(bfhi(hv.y) * inv) + 128;
  int q4 = (int)rintf(bflo(hv.z) * inv) + 128, q5 = (int)rintf(bfhi(hv.z) * inv) + 128;
  int q6 = (int)rintf(bflo(hv.w) * inv) + 128, q7 = (int)rintf(bfhi(hv.w) * inv) + 128;
  uint2 r;
  r.x = (u32)q0 | ((u32)q1 << 8) | ((u32)q2 << 16) | ((u32)q3 << 24);
  r.y = (u32)q4 | ((u32)q5 << 8) | ((u32)q6 << 16) | ((u32)q7 << 24);
  return r;
}
__device__ __forceinline__ float habs8(uint4 hv) {
  float m = fabsf(bflo(hv.x));
  m = fmaxf(m, fabsf(bfhi(hv.x))); m = fmaxf(m, fabsf(bflo(hv.y)));
  m = fmaxf(m, fabsf(bfhi(hv.y))); m = fmaxf(m, fabsf(bflo(hv.z)));
  m = fmaxf(m, fabsf(bfhi(hv.z))); m = fmaxf(m, fabsf(bflo(hv.w)));
  m = fmaxf(m, fabsf(bfhi(hv.w)));
  return m;
}

// ---------------- sort pass 1: coarse histogram ----------------
__global__ void __launch_bounds__(256) k_hist_c(const int* __restrict__ dst,
                                                int* __restrict__ ch) {
  __shared__ int h[NCOARSE];
  if (threadIdx.x < NCOARSE) h[threadIdx.x] = 0;
  __syncthreads();
  int i = blockIdx.x * 256 + threadIdx.x, stride = gridDim.x * 256;
  for (; i < NE; i += stride) atomicAdd(&h[dst[i] >> 10], 1);
  __syncthreads();
  if (threadIdx.x < NCOARSE && h[threadIdx.x]) atomicAdd(&ch[threadIdx.x], h[threadIdx.x]);
}

// ---------------- sort pass 2: coarse scatter ----------------
__global__ void __launch_bounds__(256) k_scat1(const int* __restrict__ src,
                                               const int* __restrict__ dst,
                                               const int* __restrict__ ch,
                                               int* __restrict__ reserve,
                                               u32* __restrict__ pairs1) {
  __shared__ int coffL[NCOARSE];
  __shared__ int h[NCOARSE], base[NCOARSE];
  int t = threadIdx.x;
  if (t < NCOARSE) { h[t] = 0; coffL[t] = ch[t]; }
  __syncthreads();
  if (t == 0) {
    int acc = 0;
    for (int i = 0; i < NCOARSE; i++) { int v = coffL[i]; coffL[i] = acc; acc += v; }
  }
  int e0 = blockIdx.x * SC_CH;
  int myc[8]; u32 mypk[8];
#pragma unroll
  for (int q = 0; q < 8; q++) {
    int e = e0 + q * 256 + t;
    if (e < NE) {
      int d = dst[e], s = src[e];
      myc[q] = d >> 10;
      mypk[q] = (u32)s | ((u32)(d & 1023) << 17);
      atomicAdd(&h[myc[q]], 1);
    } else myc[q] = -1;
  }
  __syncthreads();
  if (t < NCOARSE) {
    base[t] = (h[t] > 0) ? (coffL[t] + atomicAdd(&reserve[t], h[t])) : 0;
    h[t] = 0;
  }
  __syncthreads();
#pragma unroll
  for (int q = 0; q < 8; q++) {
    if (myc[q] >= 0) {
      int p = atomicAdd(&h[myc[q]], 1);
      pairs1[base[myc[q]] + p] = mypk[q];
    }
  }
}

// ---------------- sort pass 3: per-bucket CSR build in LDS (src-phase partition) ----------------
// Per node: edges partitioned into [src<SPLIT | src>=SPLIT]; mid[n] = boundary.
__global__ void __launch_bounds__(256) k_fill3(const u32* __restrict__ pairs1,
                                               const int* __restrict__ ch,
                                               int* __restrict__ row,
                                               int* __restrict__ mid,
                                               int* __restrict__ csr) {
  __shared__ int coffL[NCOARSE + 1];
  __shared__ int lcnt[2048];   // (node,phase)
  __shared__ int loff[2048];
  __shared__ int sd[256];
  __shared__ u32 stage[20480];
  int c = blockIdx.x, t = threadIdx.x;
  if (t < NCOARSE) coffL[t] = ch[t];
  __syncthreads();
  if (t == 0) {
    int acc = 0;
    for (int i = 0; i < NCOARSE; i++) { int v = coffL[i]; coffL[i] = acc; acc += v; }
    coffL[NCOARSE] = acc;
  }
  for (int i = t; i < 2048; i += 256) lcnt[i] = 0;
  __syncthreads();
  int es = coffL[c], ee = coffL[c + 1];
  int m = ee - es;
  int nbase = c << 10;
  int nodes_in = NN - nbase; if (nodes_in > 1024) nodes_in = 1024;
  for (int i = es + t; i < ee; i += 256) {
    u32 pk = pairs1[i];
    int dl = (pk >> 17) & 1023;
    int ph = ((pk & 0x1FFFFu) >= SPLIT) ? 1 : 0;
    atomicAdd(&lcnt[dl * 2 + ph], 1);
  }
  __syncthreads();
  int b8 = t * 8;
  int cv[8]; int s8 = 0;
#pragma unroll
  for (int j = 0; j < 8; j++) { cv[j] = lcnt[b8 + j]; s8 += cv[j]; }
  sd[t] = s8;
  __syncthreads();
  for (int o = 1; o < 256; o <<= 1) {
    int x = (t >= o) ? sd[t - o] : 0;
    __syncthreads();
    sd[t] += x;
    __syncthreads();
  }
  int run = sd[t] - s8;
#pragma unroll
  for (int j = 0; j < 8; j++) { loff[b8 + j] = run; run += cv[j]; }
  __syncthreads();
  for (int i = t; i < nodes_in; i += 256) {
    row[nbase + i] = es + loff[2 * i];
    mid[nbase + i] = es + loff[2 * i + 1];
  }
  if (c == NCOARSE - 1 && t == 0) row[NN] = NE;
  for (int i = t; i < 2048; i += 256) lcnt[i] = loff[i];   // cursors
  __syncthreads();
  if (m <= 20480) {
    for (int i = es + t; i < ee; i += 256) {
      u32 pk = pairs1[i];
      int dl = (pk >> 17) & 1023;
      u32 s = pk & 0x1FFFFu;
      int ph = (s >= SPLIT) ? 1 : 0;
      int p = atomicAdd(&lcnt[dl * 2 + ph], 1);
      stage[p] = s;
    }
    __syncthreads();
    for (int i = t; i < m; i += 256) csr[es + i] = (int)stage[i];
  } else {   // defensive fallback
    for (int i = es + t; i < ee; i += 256) {
      u32 pk = pairs1[i];
      int dl = (pk >> 17) & 1023;
      u32 s = pk & 0x1FFFFu;
      int ph = (s >= SPLIT) ? 1 : 0;
      int p = atomicAdd(&lcnt[dl * 2 + ph], 1);
      csr[es + p] = (int)s;
    }
  }
}

// ---------------- yb0 = quant(x @ c1_w1), MFMA (K=128); also zeroes ctrl ----------------
__global__ void __launch_bounds__(256) k_gemm_x_mfma(const float* __restrict__ x,
                                                     const float* __restrict__ w,
                                                     u8* __restrict__ qt,
                                                     float* __restrict__ scal,
                                                     int* __restrict__ ctrl) {
  if (blockIdx.x == 0) ctrl[threadIdx.x] = 0;
  __shared__ __align__(16) u16 wT[64][136];
  __shared__ __align__(16) u16 ht[4][32][72];
  int tid = threadIdx.x;
  for (int idx = tid; idx < 8192; idx += 256) {
    int k = idx >> 6, n = idx & 63;
    wT[n][k] = f2bf(w[idx]);
  }
  __syncthreads();
  int wid = tid >> 6, lane = tid & 63;
  int grp = blockIdx.x * 4 + wid;
  if (grp >= NN / 32) return;
  int g0 = grp * 32;
  int mrow = lane & 15;
  int kc8 = (lane >> 4) * 8;
  int q4 = (lane >> 4) * 4;
  bf16x8 a[2][4];
#pragma unroll
  for (int mt = 0; mt < 2; mt++) {
    const float* xr = x + (size_t)(g0 + mt * 16 + mrow) * 128;
#pragma unroll
    for (int kc = 0; kc < 4; kc++) {
      float4 v0 = *(const float4*)(xr + kc * 32 + kc8);
      float4 v1 = *(const float4*)(xr + kc * 32 + kc8 + 4);
      FragCvt fc;
      fc.s[0] = f2bf(v0.x); fc.s[1] = f2bf(v0.y); fc.s[2] = f2bf(v0.z); fc.s[3] = f2bf(v0.w);
      fc.s[4] = f2bf(v1.x); fc.s[5] = f2bf(v1.y); fc.s[6] = f2bf(v1.z); fc.s[7] = f2bf(v1.w);
      a[mt][kc] = fc.b;
    }
  }
  f32x4 zero = {0.f, 0.f, 0.f, 0.f};
  f32x4 acc[2][4];
#pragma unroll
  for (int nt = 0; nt < 4; nt++) {
    bf16x8 bf[4];
#pragma unroll
    for (int kc = 0; kc < 4; kc++)
      bf[kc] = frag_u16(&wT[nt * 16 + mrow][kc * 32 + kc8]);
#pragma unroll
    for (int mt = 0; mt < 2; mt++) {
      f32x4 c = __builtin_amdgcn_mfma_f32_16x16x32_bf16(a[mt][0], bf[0], zero, 0, 0, 0);
      c = __builtin_amdgcn_mfma_f32_16x16x32_bf16(a[mt][1], bf[1], c, 0, 0, 0);
      c = __builtin_amdgcn_mfma_f32_16x16x32_bf16(a[mt][2], bf[2], c, 0, 0, 0);
      c = __builtin_amdgcn_mfma_f32_16x16x32_bf16(a[mt][3], bf[3], c, 0, 0, 0);
      acc[mt][nt] = c;
    }
  }
#pragma unroll
  for (int mt = 0; mt < 2; mt++)
#pragma unroll
    for (int nt = 0; nt < 4; nt++)
#pragma unroll
      for (int r = 0; r < 4; r++)
        ht[wid][mt * 16 + q4 + r][nt * 16 + mrow] = f2bf(acc[mt][nt][r]);
  asm volatile("s_waitcnt lgkmcnt(0)" ::: "memory");
#pragma unroll
  for (int it = 0; it < 4; it++) {
    int idx = it * 64 + lane;
    int rw = idx >> 3, ch2 = idx & 7;
    uint4 hv = *(const uint4*)&ht[wid][rw][ch2 * 8];
    float m = habs8(hv);
    m = fmaxf(m, __shfl_xor(m, 1));
    m = fmaxf(m, __shfl_xor(m, 2));
    m = fmaxf(m, __shfl_xor(m, 4));
    float inv = (m > 0.f) ? 127.0f / m : 0.f;
    uint2 qv = q8b(hv, inv);
    *(uint2*)(qt + (size_t)(g0 + rw) * 64 + ch2 * 8) = qv;
    if (ch2 == 0) scal[g0 + rw] = m * (1.0f / 127.0f);
  }
}

// ---------------- aggregation: ub = bf16(relu((1+eps)*y + sum_nbr y + b1)) ----------------
// biased-u8 gather in 2 src-phases (each phase's table half is L2-resident).
__global__ void __launch_bounds__(256) k_agg(
    const u8* __restrict__ qt, const float* __restrict__ scal,
    const int* __restrict__ row, const int* __restrict__ mid, const int* __restrict__ csr,
    const float* __restrict__ epsv, int ei, const float* __restrict__ b1,
    u16* __restrict__ ub) {
  int t = blockIdx.x * 256 + threadIdx.x;
  int n = t >> 2, g = t & 3;
  if (n >= NN) return;
  const u8* bp = qt + g * 16;
  float a[16];
#pragma unroll
  for (int j = 0; j < 16; j++) a[j] = 0.f;
  float ssum = 0.f;
  int rs = row[n], md = mid[n], re = row[n + 1];
#define DQ16(qv, sc) { \
    ssum += sc; \
    a[0]  = fmaf(sc, ub0((qv).x), a[0]);  a[1]  = fmaf(sc, ub1((qv).x), a[1]); \
    a[2]  = fmaf(sc, ub2((qv).x), a[2]);  a[3]  = fmaf(sc, ub3((qv).x), a[3]); \
    a[4]  = fmaf(sc, ub0((qv).y), a[4]);  a[5]  = fmaf(sc, ub1((qv).y), a[5]); \
    a[6]  = fmaf(sc, ub2((qv).y), a[6]);  a[7]  = fmaf(sc, ub3((qv).y), a[7]); \
    a[8]  = fmaf(sc, ub0((qv).z), a[8]);  a[9]  = fmaf(sc, ub1((qv).z), a[9]); \
    a[10] = fmaf(sc, ub2((qv).z), a[10]); a[11] = fmaf(sc, ub3((qv).z), a[11]); \
    a[12] = fmaf(sc, ub0((qv).w), a[12]); a[13] = fmaf(sc, ub1((qv).w), a[13]); \
    a[14] = fmaf(sc, ub2((qv).w), a[14]); a[15] = fmaf(sc, ub3((qv).w), a[15]); }
  for (int sgi = 0; sgi < 2; sgi++) {
    int i = (sgi == 0) ? rs : md;
    int end = (sgi == 0) ? md : re;
    for (; i + 8 <= end; i += 8) {
      int sidx[8];
#pragma unroll
      for (int q = 0; q < 8; q++) sidx[q] = csr[i + q];
      uint4 v[8]; float sc[8];
#pragma unroll
      for (int q = 0; q < 8; q++) {
        v[q] = *(const uint4*)(bp + (size_t)sidx[q] * 64);
        sc[q] = scal[sidx[q]];
      }
#pragma unroll
      for (int q = 0; q < 8; q++) DQ16(v[q], sc[q]);
    }
    if (i + 4 <= end) {
      int sidx[4];
#pragma unroll
      for (int q = 0; q < 4; q++) sidx[q] = csr[i + q];
      uint4 v[4]; float sc[4];
#pragma unroll
      for (int q = 0; q < 4; q++) {
        v[q] = *(const uint4*)(bp + (size_t)sidx[q] * 64);
        sc[q] = scal[sidx[q]];
      }
#pragma unroll
      for (int q = 0; q < 4; q++) DQ16(v[q], sc[q]);
      i += 4;
    }
    for (; i < end; ++i) {
      int s = csr[i];
      uint4 v0 = *(const uint4*)(bp + (size_t)s * 64);
      float sc = scal[s];
      DQ16(v0, sc);
    }
  }
#undef DQ16
  uint4 sv = *(const uint4*)(bp + (size_t)n * 64);
  float ssc = scal[n];
  float e1 = 1.0f + epsv[ei];
  int fb = g * 16;
  float nk = -128.0f;
  float r[16];
  {
    float s_[16] = {
      ssc * (ub0(sv.x) - 128.f), ssc * (ub1(sv.x) - 128.f),
      ssc * (ub2(sv.x) - 128.f), ssc * (ub3(sv.x) - 128.f),
      ssc * (ub0(sv.y) - 128.f), ssc * (ub1(sv.y) - 128.f),
      ssc * (ub2(sv.y) - 128.f), ssc * (ub3(sv.y) - 128.f),
      ssc * (ub0(sv.z) - 128.f), ssc * (ub1(sv.z) - 128.f),
      ssc * (ub2(sv.z) - 128.f), ssc * (ub3(sv.z) - 128.f),
      ssc * (ub0(sv.w) - 128.f), ssc * (ub1(sv.w) - 128.f),
      ssc * (ub2(sv.w) - 128.f), ssc * (ub3(sv.w) - 128.f)};
#pragma unroll
    for (int j = 0; j < 16; j++) {
      float aj = fmaf(nk, ssum, a[j]);           // remove bias
      r[j] = fmaxf(fmaf(e1, s_[j], aj + b1[fb + j]), 0.f);
    }
  }
  uint4 p0, p1;
  p0.x = pkbf(r[0], r[1]);   p0.y = pkbf(r[2], r[3]);
  p0.z = pkbf(r[4], r[5]);   p0.w = pkbf(r[6], r[7]);
  p1.x = pkbf(r[8], r[9]);   p1.y = pkbf(r[10], r[11]);
  p1.z = pkbf(r[12], r[13]); p1.w = pkbf(r[14], r[15]);
  u16* up = ub + (size_t)n * 64 + fb;
  *(uint4*)up = p0;
  *(uint4*)(up + 8) = p1;
}

// ---------------- MFMA MLP: q/s out = quant( BN(relu(ub@w2+b2)) @ wn ) ----------------
__global__ void __launch_bounds__(256) k_mlp_mfma(
    const u16* __restrict__ ub, const float* __restrict__ w2, const float* __restrict__ b2,
    const float* __restrict__ gamma, const float* __restrict__ beta,
    const float* __restrict__ mean, const float* __restrict__ var,
    const float* __restrict__ wn, u8* __restrict__ qt, float* __restrict__ scal) {
  __shared__ __align__(16) u16 w2T[64][72];
  __shared__ __align__(16) u16 wnT[64][72];
  __shared__ __align__(16) u16 ht[4][32][72];
  int tid = threadIdx.x;
  for (int idx = tid; idx < 4096; idx += 256) {
    int k = idx >> 6, n = idx & 63;
    w2T[n][k] = f2bf(w2[idx]);
    wnT[n][k] = f2bf(wn[idx]);
  }
  __syncthreads();
  int wid = tid >> 6, lane = tid & 63;
  int grp = blockIdx.x * 4 + wid;
  if (grp >= NN / 32) return;
  int g0 = grp * 32;
  int mrow = lane & 15;
  int kc8 = (lane >> 4) * 8;
  int q4 = (lane >> 4) * 4;
  float bb[4], gl[4], be[4], mn[4], rv[4];
#pragma unroll
  for (int nt = 0; nt < 4; nt++) {
    int j = nt * 16 + mrow;
    bb[nt] = b2[j]; gl[nt] = gamma[j]; be[nt] = beta[j]; mn[nt] = mean[j];
    rv[nt] = rsqrtf(var[j] + BN_EPS);
  }
  bf16x8 a[2][2];
#pragma unroll
  for (int mt = 0; mt < 2; mt++)
#pragma unroll
    for (int kc = 0; kc < 2; kc++)
      a[mt][kc] = frag_u16(ub + (size_t)(g0 + mt * 16 + mrow) * 64 + kc * 32 + kc8);
  f32x4 zero = {0.f, 0.f, 0.f, 0.f};
  f32x4 acc[2][4];
#pragma unroll
  for (int nt = 0; nt < 4; nt++) {
    bf16x8 b0 = frag_u16(&w2T[nt * 16 + mrow][kc8]);
    bf16x8 b1f = frag_u16(&w2T[nt * 16 + mrow][32 + kc8]);
#pragma unroll
    for (int mt = 0; mt < 2; mt++) {
      acc[mt][nt] = __builtin_amdgcn_mfma_f32_16x16x32_bf16(a[mt][0], b0, zero, 0, 0, 0);
      acc[mt][nt] = __builtin_amdgcn_mfma_f32_16x16x32_bf16(a[mt][1], b1f, acc[mt][nt], 0, 0, 0);
    }
  }
#pragma unroll
  for (int mt = 0; mt < 2; mt++)
#pragma unroll
    for (int nt = 0; nt < 4; nt++)
#pragma unroll
      for (int r = 0; r < 4; r++) {
        float v = fmaxf(acc[mt][nt][r] + bb[nt], 0.f);
        float h = fmaf(gl[nt] * (v - mn[nt]), rv[nt], be[nt]);
        ht[wid][mt * 16 + q4 + r][nt * 16 + mrow] = f2bf(h);
      }
  asm volatile("s_waitcnt lgkmcnt(0)" ::: "memory");
  bf16x8 a2[2][2];
#pragma unroll
  for (int mt = 0; mt < 2; mt++)
#pragma unroll
    for (int kc = 0; kc < 2; kc++)
      a2[mt][kc] = frag_u16(&ht[wid][mt * 16 + mrow][kc * 32 + kc8]);
  f32x4 ac2[2][4];
#pragma unroll
  for (int nt = 0; nt < 4; nt++) {
    bf16x8 b0 = frag_u16(&wnT[nt * 16 + mrow][kc8]);
    bf16x8 b1f = frag_u16(&wnT[nt * 16 + mrow][32 + kc8]);
#pragma unroll
    for (int mt = 0; mt < 2; mt++) {
      ac2[mt][nt] = __builtin_amdgcn_mfma_f32_16x16x32_bf16(a2[mt][0], b0, zero, 0, 0, 0);
      ac2[mt][nt] = __builtin_amdgcn_mfma_f32_16x16x32_bf16(a2[mt][1], b1f, ac2[mt][nt], 0, 0, 0);
    }
  }
  asm volatile("s_waitcnt lgkmcnt(0)" ::: "memory");
#pragma unroll
  for (int mt = 0; mt < 2; mt++)
#pragma unroll
    for (int nt = 0; nt < 4; nt++)
#pragma unroll
      for (int r = 0; r < 4; r++)
        ht[wid][mt * 16 + q4 + r][nt * 16 + mrow] = f2bf(ac2[mt][nt][r]);
  asm volatile("s_waitcnt lgkmcnt(0)" ::: "memory");
#pragma unroll
  for (int it = 0; it < 4; it++) {
    int idx = it * 64 + lane;
    int rw = idx >> 3, ch2 = idx & 7;
    uint4 hv = *(const uint4*)&ht[wid][rw][ch2 * 8];
    float m = habs8(hv);
    m = fmaxf(m, __shfl_xor(m, 1));
    m = fmaxf(m, __shfl_xor(m, 2));
    m = fmaxf(m, __shfl_xor(m, 4));
    float inv = (m > 0.f) ? 127.0f / m : 0.f;
    uint2 qv = q8b(hv, inv);
    *(uint2*)(qt + (size_t)(g0 + rw) * 64 + ch2 * 8) = qv;
    if (ch2 == 0) scal[g0 + rw] = m * (1.0f / 127.0f);
  }
}

// ---------------- MFMA final MLP + head ----------------
__global__ void __launch_bounds__(256) k_mlp_final_mfma(
    const u16* __restrict__ ub, const float* __restrict__ w2, const float* __restrict__ b2,
    const float* __restrict__ gamma, const float* __restrict__ beta,
    const float* __restrict__ mean, const float* __restrict__ var,
    const float* __restrict__ l1w, const float* __restrict__ l1b,
    const float* __restrict__ l2w, const float* __restrict__ l2b,
    float* __restrict__ out) {
  __shared__ __align__(16) u16 w2T[64][72];
  __shared__ __align__(16) u16 l1T[64][72];
  __shared__ __align__(16) u16 l2T[48][72];
  __shared__ __align__(16) u16 ht[4][32][72];
  int tid = threadIdx.x;
  for (int idx = tid; idx < 4096; idx += 256) {
    int k = idx >> 6, n = idx & 63;
    w2T[n][k] = f2bf(w2[idx]);
    l1T[n][k] = f2bf(l1w[idx]);
  }
  for (int idx = tid; idx < 3072; idx += 256) {
    int n = idx >> 6, k = idx & 63;
    l2T[n][k] = f2bf((n < 40) ? l2w[k * 40 + n] : 0.f);
  }
  __syncthreads();
  int wid = tid >> 6, lane = tid & 63;
  int grp = blockIdx.x * 4 + wid;
  if (grp >= NN / 32) return;
  int g0 = grp * 32;
  int mrow = lane & 15;
  int kc8 = (lane >> 4) * 8;
  int q4 = (lane >> 4) * 4;
  float bb[4], gl[4], be[4], mn[4], rv[4], l1bv[4];
#pragma unroll
  for (int nt = 0; nt < 4; nt++) {
    int j = nt * 16 + mrow;
    bb[nt] = b2[j]; gl[nt] = gamma[j]; be[nt] = beta[j]; mn[nt] = mean[j];
    rv[nt] = rsqrtf(var[j] + BN_EPS); l1bv[nt] = l1b[j];
  }
  float l2bv[3];
#pragma unroll
  for (int nt = 0; nt < 3; nt++) {
    int j = nt * 16 + mrow;
    l2bv[nt] = (j < 40) ? l2b[j] : 0.f;
  }
  bf16x8 a[2][2];
#pragma unroll
  for (int mt = 0; mt < 2; mt++)
#pragma unroll
    for (int kc = 0; kc < 2; kc++)
      a[mt][kc] = frag_u16(ub + (size_t)(g0 + mt * 16 + mrow) * 64 + kc * 32 + kc8);
  f32x4 zero = {0.f, 0.f, 0.f, 0.f};
  f32x4 acc[2][4];
#pragma unroll
  for (int nt = 0; nt < 4; nt++) {
    bf16x8 b0 = frag_u16(&w2T[nt * 16 + mrow][kc8]);
    bf16x8 b1f = frag_u16(&w2T[nt * 16 + mrow][32 + kc8]);
#pragma unroll
    for (int mt = 0; mt < 2; mt++) {
      acc[mt][nt] = __builtin_amdgcn_mfma_f32_16x16x32_bf16(a[mt][0], b0, zero, 0, 0, 0);
      acc[mt][nt] = __builtin_amdgcn_mfma_f32_16x16x32_bf16(a[mt][1], b1f, acc[mt][nt], 0, 0, 0);
    }
  }
#pragma unroll
  for (int mt = 0; mt < 2; mt++)
#pragma unroll
    for (int nt = 0; nt < 4; nt++)
#pragma unroll
      for (int r = 0; r < 4; r++) {
        float v = fmaxf(acc[mt][nt][r] + bb[nt], 0.f);
        float h = fmaf(gl[nt] * (v - mn[nt]), rv[nt], be[nt]);
        ht[wid][mt * 16 + q4 + r][nt * 16 + mrow] = f2bf(h);
      }
  asm volatile("s_waitcnt lgkmcnt(0)" ::: "memory");
  bf16x8 a2[2][2];
#pragma unroll
  for (int mt = 0; mt < 2; mt++)
#pragma unroll
    for (int kc = 0; kc < 2; kc++)
      a2[mt][kc] = frag_u16(&ht[wid][mt * 16 + mrow][kc * 32 + kc8]);
  f32x4 ac2[2][4];
#pragma unroll
  for (int nt = 0; nt < 4; nt++) {
    bf16x8 b0 = frag_u16(&l1T[nt * 16 + mrow][kc8]);
    bf16x8 b1f = frag_u16(&l1T[nt * 16 + mrow][32 + kc8]);
#pragma unroll
    for (int mt = 0; mt < 2; mt++) {
      ac2[mt][nt] = __builtin_amdgcn_mfma_f32_16x16x32_bf16(a2[mt][0], b0, zero, 0, 0, 0);
      ac2[mt][nt] = __builtin_amdgcn_mfma_f32_16x16x32_bf16(a2[mt][1], b1f, ac2[mt][nt], 0, 0, 0);
    }
  }
  asm volatile("s_waitcnt lgkmcnt(0)" ::: "memory");
#pragma unroll
  for (int mt = 0; mt < 2; mt++)
#pragma unroll
    for (int nt = 0; nt < 4; nt++)
#pragma unroll
      for (int r = 0; r < 4; r++) {
        float f = fmaxf(ac2[mt][nt][r] + l1bv[nt], 0.f);
        ht[wid][mt * 16 + q4 + r][nt * 16 + mrow] = f2bf(f);
      }
  asm volatile("s_waitcnt lgkmcnt(0)" ::: "memory");
  bf16x8 a3[2][2];
#pragma unroll
  for (int mt = 0; mt < 2; mt++)
#pragma unroll
    for (int kc = 0; kc < 2; kc++)
      a3[mt][kc] = frag_u16(&ht[wid][mt * 16 + mrow][kc * 32 + kc8]);
  f32x4 ac3[2][3];
#pragma unroll
  for (int nt = 0; nt < 3; nt++) {
    bf16x8 b0 = frag_u16(&l2T[nt * 16 + mrow][kc8]);
    bf16x8 b1f = frag_u16(&l2T[nt * 16 + mrow][32 + kc8]);
#pragma unroll
    for (int mt = 0; mt < 2; mt++) {
      ac3[mt][nt] = __builtin_amdgcn_mfma_f32_16x16x32_bf16(a3[mt][0], b0, zero, 0, 0, 0);
      ac3[mt][nt] = __builtin_amdgcn_mfma_f32_16x16x32_bf16(a3[mt][1], b1f, ac3[mt][nt], 0, 0, 0);
    }
  }
#pragma unroll
  for (int mt = 0; mt < 2; mt++)
#pragma unroll
    for (int nt = 0; nt < 3; nt++) {
      int j = nt * 16 + mrow;
      if (j < 40) {
#pragma unroll
        for (int r = 0; r < 4; r++)
          out[(size_t)(g0 + mt * 16 + q4 + r) * 40 + j] = ac3[mt][nt][r] + l2bv[nt];
      }
    }
}

extern "C" void kernel_launch(void* const* d_in, const int* in_sizes, int n_in,
                              void* d_out, int out_size, void* d_ws, size_t ws_size,
                              hipStream_t stream) {
  const float* x   = (const float*)d_in[0];
  const int*   ei  = (const int*)d_in[1];
  const int*   src = ei;
  const int*   dst = ei + NE;
  const float* eps = (const float*)d_in[2];
  const float* c1_w1 = (const float*)d_in[3];
  const float* c1_b1 = (const float*)d_in[4];
  const float* c1_w2 = (const float*)d_in[5];
  const float* c1_b2 = (const float*)d_in[6];
  const float* c1_gamma = (const float*)d_in[7];
  const float* c1_beta  = (const float*)d_in[8];
  const float* c1_mean  = (const float*)d_in[9];
  const float* c1_var   = (const float*)d_in[10];
  const float* cw1 = (const float*)d_in[11];
  const float* cb1 = (const float*)d_in[12];
  const float* cw2 = (const float*)d_in[13];
  const float* cb2 = (const float*)d_in[14];
  const float* cgamma = (const float*)d_in[15];
  const float* cbeta  = (const float*)d_in[16];
  const float* cmean  = (const float*)d_in[17];
  const float* cvar   = (const float*)d_in[18];
  const float* lin1_w = (const float*)d_in[19];
  const float* lin1_b = (const float*)d_in[20];
  const float* lin2_w = (const float*)d_in[21];
  const float* lin2_b = (const float*)d_in[22];
  float* out = (float*)d_out;

  char* ws = (char*)d_ws;
  int* row  = (int*)(ws + OFF_ROW);
  int* ctrl = (int*)(ws + OFF_CTRL);
  int* ch      = ctrl;
  int* reserve = ctrl + 128;
  int* csr  = (int*)(ws + OFF_CSR);
  u32* pairs1 = (u32*)(ws + OFF_P1);
  u16* ubuf = (u16*)(ws + OFF_U);
  u8*  q0   = (u8*)(ws + OFF_Q0);
  float* s0 = (float*)(ws + OFF_S0);
  u8*  q1   = (u8*)(ws + OFF_Q1);
  float* s1 = (float*)(ws + OFF_S1);
  int* midp = (int*)(ws + OFF_MID);

  const int AGG_GRID = (NN * 4 + 255) / 256;    // 1563
  const int MLP_GRID = (NN / 32 + 3) / 4;       // 782

  // y0 = quant(x @ c1_w1); block 0 zeroes ctrl
  k_gemm_x_mfma<<<MLP_GRID, 256, 0, stream>>>(x, c1_w1, q0, s0, ctrl);

  k_hist_c<<<512, 256, 0, stream>>>(dst, ch);
  k_scat1<<<(NE + SC_CH - 1) / SC_CH, 256, 0, stream>>>(src, dst, ch, reserve, pairs1);
  k_fill3<<<NCOARSE, 256, 0, stream>>>(pairs1, ch, row, midp, csr);

  // layer 1
  k_agg<<<AGG_GRID, 256, 0, stream>>>(q0, s0, row, midp, csr, eps, 0, c1_b1, ubuf);
  k_mlp_mfma<<<MLP_GRID, 256, 0, stream>>>(ubuf, c1_w2, c1_b2,
                                           c1_gamma, c1_beta, c1_mean, c1_var,
                                           cw1, q1, s1);
  // layer 2
  k_agg<<<AGG_GRID, 256, 0, stream>>>(q1, s1, row, midp, csr, eps, 1, cb1, ubuf);
  k_mlp_mfma<<<MLP_GRID, 256, 0, stream>>>(ubuf, cw2, cb2,
                                           cgamma, cbeta, cmean, cvar,
                                           cw1 + 64 * 64, q0, s0);
  // layer 3 + head
  k_agg<<<AGG_GRID, 256, 0, stream>>>(q0, s0, row, midp, csr, eps, 2, cb1 + 64, ubuf);
  k_mlp_final_mfma<<<MLP_GRID, 256, 0, stream>>>(ubuf, cw2 + 64 * 64, cb2 + 64,
                                                 cgamma + 64, cbeta + 64, cmean + 64, cvar + 64,
                                                 lin1_w, lin1_b, lin2_w, lin2_b,
                                                 out);
}

// Round 15
// 224.698 us; speedup vs baseline: 1.0267x; 1.0267x over previous
//
#include <hip/hip_runtime.h>

#define NN 100000
#define NE 1600000
#define BN_EPS 1e-5f
#define NCOARSE 98   // ceil(NN/1024)
#define SC_CH 2048

typedef unsigned int u32;
typedef unsigned short u16;
typedef signed char s8;

// ---- workspace layout (bytes) ----
static constexpr size_t OFF_ROW  = 0;                    // (NN+1) ints
static constexpr size_t OFF_CTRL = 512u * 1024;          // ch[0..127], reserve[128..255]
static constexpr size_t OFF_CSR  = 1u << 20;             // NE ints (6.4 MB)
static constexpr size_t OFF_U    = 8u << 20;             // ub bf16 [NN][64] (12.8 MB)
static constexpr size_t OFF_P1   = OFF_U;                // alias: pairs1 dead before ub live
static constexpr size_t OFF_Q0   = 22u << 20;            // int8 [NN][64] (6.4 MB)
static constexpr size_t OFF_S0   = 30u << 20;            // float [NN] (400 KB)
static constexpr size_t OFF_Q1   = 32u << 20;            // int8 [NN][64]
static constexpr size_t OFF_S1   = 40u << 20;            // float [NN]

__device__ __forceinline__ u16 f2bf(float f) {
  u32 u = __float_as_uint(f);
  return (u16)((u + 0x7fffu + ((u >> 16) & 1u)) >> 16);
}
__device__ __forceinline__ float bflo(u32 u) { return __uint_as_float(u << 16); }
__device__ __forceinline__ float bfhi(u32 u) { return __uint_as_float(u & 0xffff0000u); }
__device__ __forceinline__ u32 pkbf(float lo, float hi) {
  return (u32)f2bf(lo) | ((u32)f2bf(hi) << 16);
}

// ---- MFMA types ----
typedef __bf16 bf16x8 __attribute__((ext_vector_type(8)));
typedef float f32x4 __attribute__((ext_vector_type(4)));
union FragCvt { uint4 u; bf16x8 b; u16 s[8]; };
__device__ __forceinline__ bf16x8 frag_u16(const u16* p) {
  FragCvt c; c.u = *(const uint4*)p; return c.b;
}

// quantize 8 bf16 (as uint4) to int8x8 given inv = 127/rowmax
__device__ __forceinline__ uint2 q8(uint4 hv, float inv) {
  float v0 = bflo(hv.x), v1 = bfhi(hv.x), v2 = bflo(hv.y), v3 = bfhi(hv.y);
  float v4 = bflo(hv.z), v5 = bfhi(hv.z), v6 = bflo(hv.w), v7 = bfhi(hv.w);
  int q0 = (int)rintf(v0 * inv), q1 = (int)rintf(v1 * inv);
  int q2 = (int)rintf(v2 * inv), q3 = (int)rintf(v3 * inv);
  int q4 = (int)rintf(v4 * inv), q5 = (int)rintf(v5 * inv);
  int q6 = (int)rintf(v6 * inv), q7 = (int)rintf(v7 * inv);
  uint2 r;
  r.x = (u32)(q0 & 0xff) | ((u32)(q1 & 0xff) << 8) | ((u32)(q2 & 0xff) << 16) | ((u32)(q3 & 0xff) << 24);
  r.y = (u32)(q4 & 0xff) | ((u32)(q5 & 0xff) << 8) | ((u32)(q6 & 0xff) << 16) | ((u32)(q7 & 0xff) << 24);
  return r;
}
__device__ __forceinline__ float habs8(uint4 hv) {
  float m = fabsf(bflo(hv.x));
  m = fmaxf(m, fabsf(bfhi(hv.x))); m = fmaxf(m, fabsf(bflo(hv.y)));
  m = fmaxf(m, fabsf(bfhi(hv.y))); m = fmaxf(m, fabsf(bflo(hv.z)));
  m = fmaxf(m, fabsf(bfhi(hv.z))); m = fmaxf(m, fabsf(bflo(hv.w)));
  m = fmaxf(m, fabsf(bfhi(hv.w)));
  return m;
}

// ---------------- sort pass 1: coarse histogram ----------------
__global__ void __launch_bounds__(256) k_hist_c(const int* __restrict__ dst,
                                                int* __restrict__ ch) {
  __shared__ int h[NCOARSE];
  if (threadIdx.x < NCOARSE) h[threadIdx.x] = 0;
  __syncthreads();
  int i = blockIdx.x * 256 + threadIdx.x, stride = gridDim.x * 256;
  for (; i < NE; i += stride) atomicAdd(&h[dst[i] >> 10], 1);
  __syncthreads();
  if (threadIdx.x < NCOARSE && h[threadIdx.x]) atomicAdd(&ch[threadIdx.x], h[threadIdx.x]);
}

// ---------------- sort pass 2: coarse scatter ----------------
__global__ void __launch_bounds__(256) k_scat1(const int* __restrict__ src,
                                               const int* __restrict__ dst,
                                               const int* __restrict__ ch,
                                               int* __restrict__ reserve,
                                               u32* __restrict__ pairs1) {
  __shared__ int coffL[NCOARSE];
  __shared__ int h[NCOARSE], base[NCOARSE];
  int t = threadIdx.x;
  if (t < NCOARSE) { h[t] = 0; coffL[t] = ch[t]; }
  __syncthreads();
  if (t == 0) {
    int acc = 0;
    for (int i = 0; i < NCOARSE; i++) { int v = coffL[i]; coffL[i] = acc; acc += v; }
  }
  int e0 = blockIdx.x * SC_CH;
  int myc[8]; u32 mypk[8];
#pragma unroll
  for (int q = 0; q < 8; q++) {
    int e = e0 + q * 256 + t;
    if (e < NE) {
      int d = dst[e], s = src[e];
      myc[q] = d >> 10;
      mypk[q] = (u32)s | ((u32)(d & 1023) << 17);
      atomicAdd(&h[myc[q]], 1);
    } else myc[q] = -1;
  }
  __syncthreads();
  if (t < NCOARSE) {
    base[t] = (h[t] > 0) ? (coffL[t] + atomicAdd(&reserve[t], h[t])) : 0;
    h[t] = 0;
  }
  __syncthreads();
#pragma unroll
  for (int q = 0; q < 8; q++) {
    if (myc[q] >= 0) {
      int p = atomicAdd(&h[myc[q]], 1);
      pairs1[base[myc[q]] + p] = mypk[q];
    }
  }
}

// ---------------- sort pass 3: per-bucket CSR build in LDS ----------------
__global__ void __launch_bounds__(256) k_fill3(const u32* __restrict__ pairs1,
                                               const int* __restrict__ ch,
                                               int* __restrict__ row,
                                               int* __restrict__ csr) {
  __shared__ int coffL[NCOARSE + 1];
  __shared__ int lcnt[1024];
  __shared__ int loff[1024];
  __shared__ int sd[256];
  __shared__ u32 stage[20480];
  int c = blockIdx.x, t = threadIdx.x;
  if (t < NCOARSE) coffL[t] = ch[t];
  __syncthreads();
  if (t == 0) {
    int acc = 0;
    for (int i = 0; i < NCOARSE; i++) { int v = coffL[i]; coffL[i] = acc; acc += v; }
    coffL[NCOARSE] = acc;
  }
  for (int i = t; i < 1024; i += 256) lcnt[i] = 0;
  __syncthreads();
  int es = coffL[c], ee = coffL[c + 1];
  int m = ee - es;
  int nbase = c << 10;
  int nodes_in = NN - nbase; if (nodes_in > 1024) nodes_in = 1024;
  for (int i = es + t; i < ee; i += 256)
    atomicAdd(&lcnt[(pairs1[i] >> 17) & 1023], 1);
  __syncthreads();
  int b4 = t * 4;
  int c0 = lcnt[b4], c1 = lcnt[b4 + 1], c2 = lcnt[b4 + 2], c3 = lcnt[b4 + 3];
  int s4 = c0 + c1 + c2 + c3;
  sd[t] = s4;
  __syncthreads();
  for (int o = 1; o < 256; o <<= 1) {
    int x = (t >= o) ? sd[t - o] : 0;
    __syncthreads();
    sd[t] += x;
    __syncthreads();
  }
  int run = sd[t] - s4;
  loff[b4] = run;     run += c0;
  loff[b4 + 1] = run; run += c1;
  loff[b4 + 2] = run; run += c2;
  loff[b4 + 3] = run;
  __syncthreads();
  for (int i = t; i < nodes_in; i += 256) row[nbase + i] = es + loff[i];
  if (c == NCOARSE - 1 && t == 0) row[NN] = NE;
  for (int i = t; i < 1024; i += 256) lcnt[i] = loff[i];
  __syncthreads();
  if (m <= 20480) {
    for (int i = es + t; i < ee; i += 256) {
      u32 pk = pairs1[i];
      int p = atomicAdd(&lcnt[(pk >> 17) & 1023], 1);
      stage[p] = pk & 0x1FFFFu;
    }
    __syncthreads();
    for (int i = t; i < m; i += 256) csr[es + i] = (int)stage[i];
  } else {
    for (int i = es + t; i < ee; i += 256) {
      u32 pk = pairs1[i];
      int p = atomicAdd(&lcnt[(pk >> 17) & 1023], 1);
      csr[es + p] = (int)(pk & 0x1FFFFu);
    }
  }
}

// ---------------- yb0 = quant(x @ c1_w1), MFMA (K=128); also zeroes ctrl ----------------
__global__ void __launch_bounds__(256) k_gemm_x_mfma(const float* __restrict__ x,
                                                     const float* __restrict__ w,
                                                     s8* __restrict__ qt,
                                                     float* __restrict__ scal,
                                                     int* __restrict__ ctrl) {
  if (blockIdx.x == 0) ctrl[threadIdx.x] = 0;
  __shared__ __align__(16) u16 wT[64][136];
  __shared__ __align__(16) u16 ht[4][32][72];
  int tid = threadIdx.x;
  for (int idx = tid; idx < 8192; idx += 256) {
    int k = idx >> 6, n = idx & 63;
    wT[n][k] = f2bf(w[idx]);
  }
  __syncthreads();
  int wid = tid >> 6, lane = tid & 63;
  int grp = blockIdx.x * 4 + wid;
  if (grp >= NN / 32) return;
  int g0 = grp * 32;
  int mrow = lane & 15;
  int kc8 = (lane >> 4) * 8;
  int q4 = (lane >> 4) * 4;
  bf16x8 a[2][4];
#pragma unroll
  for (int mt = 0; mt < 2; mt++) {
    const float* xr = x + (size_t)(g0 + mt * 16 + mrow) * 128;
#pragma unroll
    for (int kc = 0; kc < 4; kc++) {
      float4 v0 = *(const float4*)(xr + kc * 32 + kc8);
      float4 v1 = *(const float4*)(xr + kc * 32 + kc8 + 4);
      FragCvt fc;
      fc.s[0] = f2bf(v0.x); fc.s[1] = f2bf(v0.y); fc.s[2] = f2bf(v0.z); fc.s[3] = f2bf(v0.w);
      fc.s[4] = f2bf(v1.x); fc.s[5] = f2bf(v1.y); fc.s[6] = f2bf(v1.z); fc.s[7] = f2bf(v1.w);
      a[mt][kc] = fc.b;
    }
  }
  f32x4 zero = {0.f, 0.f, 0.f, 0.f};
  f32x4 acc[2][4];
#pragma unroll
  for (int nt = 0; nt < 4; nt++) {
    bf16x8 bf[4];
#pragma unroll
    for (int kc = 0; kc < 4; kc++)
      bf[kc] = frag_u16(&wT[nt * 16 + mrow][kc * 32 + kc8]);
#pragma unroll
    for (int mt = 0; mt < 2; mt++) {
      f32x4 c = __builtin_amdgcn_mfma_f32_16x16x32_bf16(a[mt][0], bf[0], zero, 0, 0, 0);
      c = __builtin_amdgcn_mfma_f32_16x16x32_bf16(a[mt][1], bf[1], c, 0, 0, 0);
      c = __builtin_amdgcn_mfma_f32_16x16x32_bf16(a[mt][2], bf[2], c, 0, 0, 0);
      c = __builtin_amdgcn_mfma_f32_16x16x32_bf16(a[mt][3], bf[3], c, 0, 0, 0);
      acc[mt][nt] = c;
    }
  }
#pragma unroll
  for (int mt = 0; mt < 2; mt++)
#pragma unroll
    for (int nt = 0; nt < 4; nt++)
#pragma unroll
      for (int r = 0; r < 4; r++)
        ht[wid][mt * 16 + q4 + r][nt * 16 + mrow] = f2bf(acc[mt][nt][r]);
  asm volatile("s_waitcnt lgkmcnt(0)" ::: "memory");
#pragma unroll
  for (int it = 0; it < 4; it++) {
    int idx = it * 64 + lane;
    int rw = idx >> 3, ch2 = idx & 7;
    uint4 hv = *(const uint4*)&ht[wid][rw][ch2 * 8];
    float m = habs8(hv);
    m = fmaxf(m, __shfl_xor(m, 1));
    m = fmaxf(m, __shfl_xor(m, 2));
    m = fmaxf(m, __shfl_xor(m, 4));
    float inv = (m > 0.f) ? 127.0f / m : 0.f;
    uint2 qv = q8(hv, inv);
    *(uint2*)(qt + (size_t)(g0 + rw) * 64 + ch2 * 8) = qv;
    if (ch2 == 0) scal[g0 + rw] = m * (1.0f / 127.0f);
  }
}

// ---------------- aggregation: ub = bf16(relu((1+eps)*y + sum_nbr y + b1)) ----------------
// thread = (node, quarter): 4 thr/node x 16 feats; uint4 int8 row loads.
__global__ void __launch_bounds__(256) k_agg(
    const s8* __restrict__ qt, const float* __restrict__ scal,
    const int* __restrict__ row, const int* __restrict__ csr,
    const float* __restrict__ epsv, int ei, const float* __restrict__ b1,
    u16* __restrict__ ub) {
  int t = blockIdx.x * 256 + threadIdx.x;
  int n = t >> 2, g = t & 3;
  if (n >= NN) return;
  const s8* bp = qt + g * 16;
  float a[16];
#pragma unroll
  for (int j = 0; j < 16; j++) a[j] = 0.f;
  int rs = row[n], re = row[n + 1];
  int i = rs;
#define DQ16(qv, sc) { \
    a[0]  = fmaf(sc, (float)(int)(s8)((qv).x),       a[0]); \
    a[1]  = fmaf(sc, (float)(int)(s8)((qv).x >> 8),  a[1]); \
    a[2]  = fmaf(sc, (float)(int)(s8)((qv).x >> 16), a[2]); \
    a[3]  = fmaf(sc, (float)(int)(s8)((qv).x >> 24), a[3]); \
    a[4]  = fmaf(sc, (float)(int)(s8)((qv).y),       a[4]); \
    a[5]  = fmaf(sc, (float)(int)(s8)((qv).y >> 8),  a[5]); \
    a[6]  = fmaf(sc, (float)(int)(s8)((qv).y >> 16), a[6]); \
    a[7]  = fmaf(sc, (float)(int)(s8)((qv).y >> 24), a[7]); \
    a[8]  = fmaf(sc, (float)(int)(s8)((qv).z),       a[8]); \
    a[9]  = fmaf(sc, (float)(int)(s8)((qv).z >> 8),  a[9]); \
    a[10] = fmaf(sc, (float)(int)(s8)((qv).z >> 16), a[10]); \
    a[11] = fmaf(sc, (float)(int)(s8)((qv).z >> 24), a[11]); \
    a[12] = fmaf(sc, (float)(int)(s8)((qv).w),       a[12]); \
    a[13] = fmaf(sc, (float)(int)(s8)((qv).w >> 8),  a[13]); \
    a[14] = fmaf(sc, (float)(int)(s8)((qv).w >> 16), a[14]); \
    a[15] = fmaf(sc, (float)(int)(s8)((qv).w >> 24), a[15]); }
  for (; i + 8 <= re; i += 8) {
    int sidx[8];
#pragma unroll
    for (int q = 0; q < 8; q++) sidx[q] = csr[i + q];
    uint4 v[8]; float sc[8];
#pragma unroll
    for (int q = 0; q < 8; q++) {
      v[q] = *(const uint4*)(bp + (size_t)sidx[q] * 64);
      sc[q] = scal[sidx[q]];
    }
#pragma unroll
    for (int q = 0; q < 8; q++) DQ16(v[q], sc[q]);
  }
  if (i + 4 <= re) {
    int sidx[4];
#pragma unroll
    for (int q = 0; q < 4; q++) sidx[q] = csr[i + q];
    uint4 v[4]; float sc[4];
#pragma unroll
    for (int q = 0; q < 4; q++) {
      v[q] = *(const uint4*)(bp + (size_t)sidx[q] * 64);
      sc[q] = scal[sidx[q]];
    }
#pragma unroll
    for (int q = 0; q < 4; q++) DQ16(v[q], sc[q]);
    i += 4;
  }
  for (; i < re; ++i) {
    int s = csr[i];
    uint4 v0 = *(const uint4*)(bp + (size_t)s * 64);
    float sc = scal[s];
    DQ16(v0, sc);
  }
#undef DQ16
  uint4 sv = *(const uint4*)(bp + (size_t)n * 64);
  float ssc = scal[n];
  float e1 = 1.0f + epsv[ei];
  int fb = g * 16;
  float r[16];
  {
    u32 w0 = sv.x, w1 = sv.y, w2 = sv.z, w3 = sv.w;
    float s_[16] = {
      ssc * (float)(int)(s8)(w0),       ssc * (float)(int)(s8)(w0 >> 8),
      ssc * (float)(int)(s8)(w0 >> 16), ssc * (float)(int)(s8)(w0 >> 24),
      ssc * (float)(int)(s8)(w1),       ssc * (float)(int)(s8)(w1 >> 8),
      ssc * (float)(int)(s8)(w1 >> 16), ssc * (float)(int)(s8)(w1 >> 24),
      ssc * (float)(int)(s8)(w2),       ssc * (float)(int)(s8)(w2 >> 8),
      ssc * (float)(int)(s8)(w2 >> 16), ssc * (float)(int)(s8)(w2 >> 24),
      ssc * (float)(int)(s8)(w3),       ssc * (float)(int)(s8)(w3 >> 8),
      ssc * (float)(int)(s8)(w3 >> 16), ssc * (float)(int)(s8)(w3 >> 24)};
#pragma unroll
    for (int j = 0; j < 16; j++)
      r[j] = fmaxf(fmaf(e1, s_[j], a[j] + b1[fb + j]), 0.f);
  }
  uint4 p0, p1;
  p0.x = pkbf(r[0], r[1]);   p0.y = pkbf(r[2], r[3]);
  p0.z = pkbf(r[4], r[5]);   p0.w = pkbf(r[6], r[7]);
  p1.x = pkbf(r[8], r[9]);   p1.y = pkbf(r[10], r[11]);
  p1.z = pkbf(r[12], r[13]); p1.w = pkbf(r[14], r[15]);
  u16* up = ub + (size_t)n * 64 + fb;
  *(uint4*)up = p0;
  *(uint4*)(up + 8) = p1;
}

// ---------------- MFMA MLP: q/s out = quant( BN(relu(ub@w2+b2)) @ wn ) ----------------
__global__ void __launch_bounds__(256) k_mlp_mfma(
    const u16* __restrict__ ub, const float* __restrict__ w2, const float* __restrict__ b2,
    const float* __restrict__ gamma, const float* __restrict__ beta,
    const float* __restrict__ mean, const float* __restrict__ var,
    const float* __restrict__ wn, s8* __restrict__ qt, float* __restrict__ scal) {
  __shared__ __align__(16) u16 w2T[64][72];
  __shared__ __align__(16) u16 wnT[64][72];
  __shared__ __align__(16) u16 ht[4][32][72];
  int tid = threadIdx.x;
  for (int idx = tid; idx < 4096; idx += 256) {
    int k = idx >> 6, n = idx & 63;
    w2T[n][k] = f2bf(w2[idx]);
    wnT[n][k] = f2bf(wn[idx]);
  }
  __syncthreads();
  int wid = tid >> 6, lane = tid & 63;
  int grp = blockIdx.x * 4 + wid;
  if (grp >= NN / 32) return;
  int g0 = grp * 32;
  int mrow = lane & 15;
  int kc8 = (lane >> 4) * 8;
  int q4 = (lane >> 4) * 4;
  float bb[4], gl[4], be[4], mn[4], rv[4];
#pragma unroll
  for (int nt = 0; nt < 4; nt++) {
    int j = nt * 16 + mrow;
    bb[nt] = b2[j]; gl[nt] = gamma[j]; be[nt] = beta[j]; mn[nt] = mean[j];
    rv[nt] = rsqrtf(var[j] + BN_EPS);
  }
  bf16x8 a[2][2];
#pragma unroll
  for (int mt = 0; mt < 2; mt++)
#pragma unroll
    for (int kc = 0; kc < 2; kc++)
      a[mt][kc] = frag_u16(ub + (size_t)(g0 + mt * 16 + mrow) * 64 + kc * 32 + kc8);
  f32x4 zero = {0.f, 0.f, 0.f, 0.f};
  f32x4 acc[2][4];
#pragma unroll
  for (int nt = 0; nt < 4; nt++) {
    bf16x8 b0 = frag_u16(&w2T[nt * 16 + mrow][kc8]);
    bf16x8 b1f = frag_u16(&w2T[nt * 16 + mrow][32 + kc8]);
#pragma unroll
    for (int mt = 0; mt < 2; mt++) {
      acc[mt][nt] = __builtin_amdgcn_mfma_f32_16x16x32_bf16(a[mt][0], b0, zero, 0, 0, 0);
      acc[mt][nt] = __builtin_amdgcn_mfma_f32_16x16x32_bf16(a[mt][1], b1f, acc[mt][nt], 0, 0, 0);
    }
  }
#pragma unroll
  for (int mt = 0; mt < 2; mt++)
#pragma unroll
    for (int nt = 0; nt < 4; nt++)
#pragma unroll
      for (int r = 0; r < 4; r++) {
        float v = fmaxf(acc[mt][nt][r] + bb[nt], 0.f);
        float h = fmaf(gl[nt] * (v - mn[nt]), rv[nt], be[nt]);
        ht[wid][mt * 16 + q4 + r][nt * 16 + mrow] = f2bf(h);
      }
  asm volatile("s_waitcnt lgkmcnt(0)" ::: "memory");
  bf16x8 a2[2][2];
#pragma unroll
  for (int mt = 0; mt < 2; mt++)
#pragma unroll
    for (int kc = 0; kc < 2; kc++)
      a2[mt][kc] = frag_u16(&ht[wid][mt * 16 + mrow][kc * 32 + kc8]);
  f32x4 ac2[2][4];
#pragma unroll
  for (int nt = 0; nt < 4; nt++) {
    bf16x8 b0 = frag_u16(&wnT[nt * 16 + mrow][kc8]);
    bf16x8 b1f = frag_u16(&wnT[nt * 16 + mrow][32 + kc8]);
#pragma unroll
    for (int mt = 0; mt < 2; mt++) {
      ac2[mt][nt] = __builtin_amdgcn_mfma_f32_16x16x32_bf16(a2[mt][0], b0, zero, 0, 0, 0);
      ac2[mt][nt] = __builtin_amdgcn_mfma_f32_16x16x32_bf16(a2[mt][1], b1f, ac2[mt][nt], 0, 0, 0);
    }
  }
  asm volatile("s_waitcnt lgkmcnt(0)" ::: "memory");
#pragma unroll
  for (int mt = 0; mt < 2; mt++)
#pragma unroll
    for (int nt = 0; nt < 4; nt++)
#pragma unroll
      for (int r = 0; r < 4; r++)
        ht[wid][mt * 16 + q4 + r][nt * 16 + mrow] = f2bf(ac2[mt][nt][r]);
  asm volatile("s_waitcnt lgkmcnt(0)" ::: "memory");
#pragma unroll
  for (int it = 0; it < 4; it++) {
    int idx = it * 64 + lane;
    int rw = idx >> 3, ch2 = idx & 7;
    uint4 hv = *(const uint4*)&ht[wid][rw][ch2 * 8];
    float m = habs8(hv);
    m = fmaxf(m, __shfl_xor(m, 1));
    m = fmaxf(m, __shfl_xor(m, 2));
    m = fmaxf(m, __shfl_xor(m, 4));
    float inv = (m > 0.f) ? 127.0f / m : 0.f;
    uint2 qv = q8(hv, inv);
    *(uint2*)(qt + (size_t)(g0 + rw) * 64 + ch2 * 8) = qv;
    if (ch2 == 0) scal[g0 + rw] = m * (1.0f / 127.0f);
  }
}

// ---------------- MFMA final MLP + head ----------------
__global__ void __launch_bounds__(256) k_mlp_final_mfma(
    const u16* __restrict__ ub, const float* __restrict__ w2, const float* __restrict__ b2,
    const float* __restrict__ gamma, const float* __restrict__ beta,
    const float* __restrict__ mean, const float* __restrict__ var,
    const float* __restrict__ l1w, const float* __restrict__ l1b,
    const float* __restrict__ l2w, const float* __restrict__ l2b,
    float* __restrict__ out) {
  __shared__ __align__(16) u16 w2T[64][72];
  __shared__ __align__(16) u16 l1T[64][72];
  __shared__ __align__(16) u16 l2T[48][72];
  __shared__ __align__(16) u16 ht[4][32][72];
  int tid = threadIdx.x;
  for (int idx = tid; idx < 4096; idx += 256) {
    int k = idx >> 6, n = idx & 63;
    w2T[n][k] = f2bf(w2[idx]);
    l1T[n][k] = f2bf(l1w[idx]);
  }
  for (int idx = tid; idx < 3072; idx += 256) {
    int n = idx >> 6, k = idx & 63;
    l2T[n][k] = f2bf((n < 40) ? l2w[k * 40 + n] : 0.f);
  }
  __syncthreads();
  int wid = tid >> 6, lane = tid & 63;
  int grp = blockIdx.x * 4 + wid;
  if (grp >= NN / 32) return;
  int g0 = grp * 32;
  int mrow = lane & 15;
  int kc8 = (lane >> 4) * 8;
  int q4 = (lane >> 4) * 4;
  float bb[4], gl[4], be[4], mn[4], rv[4], l1bv[4];
#pragma unroll
  for (int nt = 0; nt < 4; nt++) {
    int j = nt * 16 + mrow;
    bb[nt] = b2[j]; gl[nt] = gamma[j]; be[nt] = beta[j]; mn[nt] = mean[j];
    rv[nt] = rsqrtf(var[j] + BN_EPS); l1bv[nt] = l1b[j];
  }
  float l2bv[3];
#pragma unroll
  for (int nt = 0; nt < 3; nt++) {
    int j = nt * 16 + mrow;
    l2bv[nt] = (j < 40) ? l2b[j] : 0.f;
  }
  bf16x8 a[2][2];
#pragma unroll
  for (int mt = 0; mt < 2; mt++)
#pragma unroll
    for (int kc = 0; kc < 2; kc++)
      a[mt][kc] = frag_u16(ub + (size_t)(g0 + mt * 16 + mrow) * 64 + kc * 32 + kc8);
  f32x4 zero = {0.f, 0.f, 0.f, 0.f};
  f32x4 acc[2][4];
#pragma unroll
  for (int nt = 0; nt < 4; nt++) {
    bf16x8 b0 = frag_u16(&w2T[nt * 16 + mrow][kc8]);
    bf16x8 b1f = frag_u16(&w2T[nt * 16 + mrow][32 + kc8]);
#pragma unroll
    for (int mt = 0; mt < 2; mt++) {
      acc[mt][nt] = __builtin_amdgcn_mfma_f32_16x16x32_bf16(a[mt][0], b0, zero, 0, 0, 0);
      acc[mt][nt] = __builtin_amdgcn_mfma_f32_16x16x32_bf16(a[mt][1], b1f, acc[mt][nt], 0, 0, 0);
    }
  }
#pragma unroll
  for (int mt = 0; mt < 2; mt++)
#pragma unroll
    for (int nt = 0; nt < 4; nt++)
#pragma unroll
      for (int r = 0; r < 4; r++) {
        float v = fmaxf(acc[mt][nt][r] + bb[nt], 0.f);
        float h = fmaf(gl[nt] * (v - mn[nt]), rv[nt], be[nt]);
        ht[wid][mt * 16 + q4 + r][nt * 16 + mrow] = f2bf(h);
      }
  asm volatile("s_waitcnt lgkmcnt(0)" ::: "memory");
  bf16x8 a2[2][2];
#pragma unroll
  for (int mt = 0; mt < 2; mt++)
#pragma unroll
    for (int kc = 0; kc < 2; kc++)
      a2[mt][kc] = frag_u16(&ht[wid][mt * 16 + mrow][kc * 32 + kc8]);
  f32x4 ac2[2][4];
#pragma unroll
  for (int nt = 0; nt < 4; nt++) {
    bf16x8 b0 = frag_u16(&l1T[nt * 16 + mrow][kc8]);
    bf16x8 b1f = frag_u16(&l1T[nt * 16 + mrow][32 + kc8]);
#pragma unroll
    for (int mt = 0; mt < 2; mt++) {
      ac2[mt][nt] = __builtin_amdgcn_mfma_f32_16x16x32_bf16(a2[mt][0], b0, zero, 0, 0, 0);
      ac2[mt][nt] = __builtin_amdgcn_mfma_f32_16x16x32_bf16(a2[mt][1], b1f, ac2[mt][nt], 0, 0, 0);
    }
  }
  asm volatile("s_waitcnt lgkmcnt(0)" ::: "memory");
#pragma unroll
  for (int mt = 0; mt < 2; mt++)
#pragma unroll
    for (int nt = 0; nt < 4; nt++)
#pragma unroll
      for (int r = 0; r < 4; r++) {
        float f = fmaxf(ac2[mt][nt][r] + l1bv[nt], 0.f);
        ht[wid][mt * 16 + q4 + r][nt * 16 + mrow] = f2bf(f);
      }
  asm volatile("s_waitcnt lgkmcnt(0)" ::: "memory");
  bf16x8 a3[2][2];
#pragma unroll
  for (int mt = 0; mt < 2; mt++)
#pragma unroll
    for (int kc = 0; kc < 2; kc++)
      a3[mt][kc] = frag_u16(&ht[wid][mt * 16 + mrow][kc * 32 + kc8]);
  f32x4 ac3[2][3];
#pragma unroll
  for (int nt = 0; nt < 3; nt++) {
    bf16x8 b0 = frag_u16(&l2T[nt * 16 + mrow][kc8]);
    bf16x8 b1f = frag_u16(&l2T[nt * 16 + mrow][32 + kc8]);
#pragma unroll
    for (int mt = 0; mt < 2; mt++) {
      ac3[mt][nt] = __builtin_amdgcn_mfma_f32_16x16x32_bf16(a3[mt][0], b0, zero, 0, 0, 0);
      ac3[mt][nt] = __builtin_amdgcn_mfma_f32_16x16x32_bf16(a3[mt][1], b1f, ac3[mt][nt], 0, 0, 0);
    }
  }
#pragma unroll
  for (int mt = 0; mt < 2; mt++)
#pragma unroll
    for (int nt = 0; nt < 3; nt++) {
      int j = nt * 16 + mrow;
      if (j < 40) {
#pragma unroll
        for (int r = 0; r < 4; r++)
          out[(size_t)(g0 + mt * 16 + q4 + r) * 40 + j] = ac3[mt][nt][r] + l2bv[nt];
      }
    }
}

extern "C" void kernel_launch(void* const* d_in, const int* in_sizes, int n_in,
                              void* d_out, int out_size, void* d_ws, size_t ws_size,
                              hipStream_t stream) {
  const float* x   = (const float*)d_in[0];
  const int*   ei  = (const int*)d_in[1];
  const int*   src = ei;
  const int*   dst = ei + NE;
  const float* eps = (const float*)d_in[2];
  const float* c1_w1 = (const float*)d_in[3];
  const float* c1_b1 = (const float*)d_in[4];
  const float* c1_w2 = (const float*)d_in[5];
  const float* c1_b2 = (const float*)d_in[6];
  const float* c1_gamma = (const float*)d_in[7];
  const float* c1_beta  = (const float*)d_in[8];
  const float* c1_mean  = (const float*)d_in[9];
  const float* c1_var   = (const float*)d_in[10];
  const float* cw1 = (const float*)d_in[11];
  const float* cb1 = (const float*)d_in[12];
  const float* cw2 = (const float*)d_in[13];
  const float* cb2 = (const float*)d_in[14];
  const float* cgamma = (const float*)d_in[15];
  const float* cbeta  = (const float*)d_in[16];
  const float* cmean  = (const float*)d_in[17];
  const float* cvar   = (const float*)d_in[18];
  const float* lin1_w = (const float*)d_in[19];
  const float* lin1_b = (const float*)d_in[20];
  const float* lin2_w = (const float*)d_in[21];
  const float* lin2_b = (const float*)d_in[22];
  float* out = (float*)d_out;

  char* ws = (char*)d_ws;
  int* row  = (int*)(ws + OFF_ROW);
  int* ctrl = (int*)(ws + OFF_CTRL);
  int* ch      = ctrl;
  int* reserve = ctrl + 128;
  int* csr  = (int*)(ws + OFF_CSR);
  u32* pairs1 = (u32*)(ws + OFF_P1);
  u16* ubuf = (u16*)(ws + OFF_U);
  s8*  q0   = (s8*)(ws + OFF_Q0);
  float* s0 = (float*)(ws + OFF_S0);
  s8*  q1   = (s8*)(ws + OFF_Q1);
  float* s1 = (float*)(ws + OFF_S1);

  const int AGG_GRID = (NN * 4 + 255) / 256;    // 1563
  const int MLP_GRID = (NN / 32 + 3) / 4;       // 782

  // y0 = quant(x @ c1_w1); block 0 zeroes ctrl
  k_gemm_x_mfma<<<MLP_GRID, 256, 0, stream>>>(x, c1_w1, q0, s0, ctrl);

  k_hist_c<<<512, 256, 0, stream>>>(dst, ch);
  k_scat1<<<(NE + SC_CH - 1) / SC_CH, 256, 0, stream>>>(src, dst, ch, reserve, pairs1);
  k_fill3<<<NCOARSE, 256, 0, stream>>>(pairs1, ch, row, csr);

  // layer 1
  k_agg<<<AGG_GRID, 256, 0, stream>>>(q0, s0, row, csr, eps, 0, c1_b1, ubuf);
  k_mlp_mfma<<<MLP_GRID, 256, 0, stream>>>(ubuf, c1_w2, c1_b2,
                                           c1_gamma, c1_beta, c1_mean, c1_var,
                                           cw1, q1, s1);
  // layer 2
  k_agg<<<AGG_GRID, 256, 0, stream>>>(q1, s1, row, csr, eps, 1, cb1, ubuf);
  k_mlp_mfma<<<MLP_GRID, 256, 0, stream>>>(ubuf, cw2, cb2,
                                           cgamma, cbeta, cmean, cvar,
                                           cw1 + 64 * 64, q0, s0);
  // layer 3 + head
  k_agg<<<AGG_GRID, 256, 0, stream>>>(q0, s0, row, csr, eps, 2, cb1 + 64, ubuf);
  k_mlp_final_mfma<<<MLP_GRID, 256, 0, stream>>>(ubuf, cw2 + 64 * 64, cb2 + 64,
                                                 cgamma + 64, cbeta + 64, cmean + 64, cvar + 64,
                                                 lin1_w, lin1_b, lin2_w, lin2_b,
                                                 out);
}